// Round 8
// baseline (272.130 us; speedup 1.0000x reference)
//
#include <hip/hip_runtime.h>

#define LN_EPS 1e-5f

constexpr int B = 4, N = 512, C = 64;
// N and N*N are powers of two: N = 1<<9.

typedef float f32x4 __attribute__((ext_vector_type(4)));  // native clang vector:
// required by __builtin_nontemporal_store (HIP's float4 is a class, rejected).

// ---------------------------------------------------------------------------
// Kernel 1: x[b,n,d] = LN(ReLU(sum_c h[b,n,c] * W[d,c] + bias[d])) * gamma + beta
// One wave (64 lanes) per (b,n) row; lane = output channel d.
// ---------------------------------------------------------------------------
__global__ __launch_bounds__(256) void mlp_ln_kernel(
    const float* __restrict__ h, const float* __restrict__ W,
    const float* __restrict__ bias, const float* __restrict__ gamma,
    const float* __restrict__ beta, float* __restrict__ x)
{
    __shared__ float sh[4][C];
    const int lane = threadIdx.x & 63;
    const int wid  = threadIdx.x >> 6;
    const int row  = blockIdx.x * 4 + wid;          // row in [0, B*N)

    // Stage h row into LDS (coalesced 256B per wave).
    sh[wid][lane] = h[row * C + lane];
    __syncthreads();

    float acc = bias[lane];
    const float* wrow = W + lane * C;               // W[d, :], d = lane
    #pragma unroll
    for (int c = 0; c < C; ++c) acc = fmaf(sh[wid][c], wrow[c], acc);

    float v = fmaxf(acc, 0.0f);                     // ReLU

    // LayerNorm across the 64 lanes (channel dim).
    float s = v;
    #pragma unroll
    for (int m = 32; m >= 1; m >>= 1) s += __shfl_xor(s, m);
    const float mu = s * (1.0f / C);
    float t = v - mu;
    float q = t * t;
    #pragma unroll
    for (int m = 32; m >= 1; m >>= 1) q += __shfl_xor(q, m);
    const float var = q * (1.0f / C);

    x[row * C + lane] = t * rsqrtf(var + LN_EPS) * gamma[lane] + beta[lane];
}

// ---------------------------------------------------------------------------
// Kernel 2: out[b,i,j,c] = softmax_c( x[b,i,c] * x[b,j,c] )
// One wave handles 4 consecutive output rows (same (b,i), consecutive j).
//   sub = lane>>4 : which of the 4 rows
//   q   = lane&15 : which channel-quad (4 channels per lane, f32x4)
// Reductions use __shfl_xor masks 1,2,4,8 — confined to 16-lane groups.
// Store: 16B/lane, 1 KB contiguous per wave, nontemporal (streaming out).
// ---------------------------------------------------------------------------
__global__ __launch_bounds__(256) void softmax_outer_kernel(
    const float* __restrict__ x, float* __restrict__ out)
{
    const int tid  = blockIdx.x * 256 + threadIdx.x;
    const int wave = tid >> 6;
    const int lane = threadIdx.x & 63;
    const int sub  = lane >> 4;
    const int q    = lane & 15;

    const int R0 = wave * 4;                 // first output row of this wave
    const int bi = R0 >> 9;                  // R0 / N  == b*N + i  (x row of i)
    const int j0 = R0 & (N - 1);             // R0 % N
    const int i  = bi & (N - 1);
    const int jrow = (bi - i) + j0 + sub;    // b*N + j (x row of j)

    const f32x4 xi = *(const f32x4*)(x + (size_t)bi   * C + q * 4);
    const f32x4 xj = *(const f32x4*)(x + (size_t)jrow * C + q * 4);

    const float d0 = xi.x * xj.x;
    const float d1 = xi.y * xj.y;
    const float d2 = xi.z * xj.z;
    const float d3 = xi.w * xj.w;

    // max over the 64 channels of this row (16-lane group reduce)
    float m = fmaxf(fmaxf(d0, d1), fmaxf(d2, d3));
    #pragma unroll
    for (int mk = 8; mk >= 1; mk >>= 1) m = fmaxf(m, __shfl_xor(m, mk));

    const float e0 = __expf(d0 - m);
    const float e1 = __expf(d1 - m);
    const float e2 = __expf(d2 - m);
    const float e3 = __expf(d3 - m);

    float s = e0 + e1 + e2 + e3;
    #pragma unroll
    for (int mk = 8; mk >= 1; mk >>= 1) s += __shfl_xor(s, mk);

    const float inv = 1.0f / s;
    f32x4 o;
    o.x = e0 * inv; o.y = e1 * inv; o.z = e2 * inv; o.w = e3 * inv;
    __builtin_nontemporal_store(o, (f32x4*)(out + (size_t)R0 * C + (size_t)lane * 4));
}

extern "C" void kernel_launch(void* const* d_in, const int* in_sizes, int n_in,
                              void* d_out, int out_size, void* d_ws, size_t ws_size,
                              hipStream_t stream) {
    const float* h     = (const float*)d_in[0];
    const float* W     = (const float*)d_in[1];
    const float* b     = (const float*)d_in[2];
    const float* gamma = (const float*)d_in[3];
    const float* beta  = (const float*)d_in[4];
    float* out = (float*)d_out;
    float* x   = (float*)d_ws;               // B*N*C floats = 512 KB scratch

    // Kernel 1: B*N = 2048 rows, 4 rows (waves) per block -> 512 blocks.
    mlp_ln_kernel<<<(B * N) / 4, 256, 0, stream>>>(h, W, b, gamma, beta, x);

    // Kernel 2: B*N*N = 1,048,576 rows, 16 rows per block -> 65,536 blocks.
    softmax_outer_kernel<<<(B * N * N) / 16, 256, 0, stream>>>(x, out);
}

// Round 12
// 268.802 us; speedup vs baseline: 1.0124x; 1.0124x over previous
//
#include <hip/hip_runtime.h>

#define LN_EPS 1e-5f

constexpr int B = 4, N = 512, C = 64;
// N and N*N are powers of two: N = 1<<9.

typedef float f32x4 __attribute__((ext_vector_type(4)));  // native clang vector:
// required by __builtin_nontemporal_store (HIP's float4 is a class, rejected).

// DPP cross-lane move within a 16-lane DPP row (VALU pipe, no LDS traffic).
// CTRL: 0xB1 = quad_perm(1,0,3,2) = xor1; 0x4E = quad_perm(2,3,0,1) = xor2;
//       0x141 = row_half_mirror (pairs across 4-quads within 8);
//       0x140 = row_mirror (pairs across 8-halves within 16).
// Each is an involution, so 4 combine stages give all 16 lanes the total.
template <int CTRL>
__device__ __forceinline__ float dpp_mov(float x) {
    const int i = __float_as_int(x);
    const int r = __builtin_amdgcn_update_dpp(i, i, CTRL, 0xF, 0xF, false);
    return __int_as_float(r);
}

// ---------------------------------------------------------------------------
// Kernel 1: x[b,n,d] = LN(ReLU(sum_c h[b,n,c] * W[d,c] + bias[d])) * gamma + beta
// One wave (64 lanes) per (b,n) row; lane = output channel d.
// (~3 us total — not on the critical path, left unchanged.)
// ---------------------------------------------------------------------------
__global__ __launch_bounds__(256) void mlp_ln_kernel(
    const float* __restrict__ h, const float* __restrict__ W,
    const float* __restrict__ bias, const float* __restrict__ gamma,
    const float* __restrict__ beta, float* __restrict__ x)
{
    __shared__ float sh[4][C];
    const int lane = threadIdx.x & 63;
    const int wid  = threadIdx.x >> 6;
    const int row  = blockIdx.x * 4 + wid;          // row in [0, B*N)

    // Stage h row into LDS (coalesced 256B per wave).
    sh[wid][lane] = h[row * C + lane];
    __syncthreads();

    float acc = bias[lane];
    const float* wrow = W + lane * C;               // W[d, :], d = lane
    #pragma unroll
    for (int c = 0; c < C; ++c) acc = fmaf(sh[wid][c], wrow[c], acc);

    float v = fmaxf(acc, 0.0f);                     // ReLU

    // LayerNorm across the 64 lanes (channel dim).
    float s = v;
    #pragma unroll
    for (int m = 32; m >= 1; m >>= 1) s += __shfl_xor(s, m);
    const float mu = s * (1.0f / C);
    float t = v - mu;
    float q = t * t;
    #pragma unroll
    for (int m = 32; m >= 1; m >>= 1) q += __shfl_xor(q, m);
    const float var = q * (1.0f / C);

    x[row * C + lane] = t * rsqrtf(var + LN_EPS) * gamma[lane] + beta[lane];
}

// ---------------------------------------------------------------------------
// Kernel 2: out[b,i,j,c] = softmax_c( x[b,i,c] * x[b,j,c] )
// One wave handles 4 consecutive output rows (same (b,i), consecutive j).
//   sub = lane>>4 : which of the 4 rows
//   q   = lane&15 : which channel-quad (4 channels per lane, f32x4)
// Reductions: 4 DPP stages within each 16-lane row (VALU pipe) — replaces
// 8 DS-pipe shuffles/wave (~79 us/CU of DS occupancy at 4096 waves/CU, the
// dominant non-store resource per the round-8 arithmetic; DS conflicts were 0
// so it was pure op count).
// Store: 16B/lane, 1 KB contiguous per wave, nontemporal (streaming out).
// ---------------------------------------------------------------------------
__global__ __launch_bounds__(256) void softmax_outer_kernel(
    const float* __restrict__ x, float* __restrict__ out)
{
    const int tid  = blockIdx.x * 256 + threadIdx.x;
    const int wave = tid >> 6;
    const int lane = threadIdx.x & 63;
    const int sub  = lane >> 4;
    const int q    = lane & 15;

    const int R0 = wave * 4;                 // first output row of this wave
    const int bi = R0 >> 9;                  // R0 / N  == b*N + i  (x row of i)
    const int j0 = R0 & (N - 1);             // R0 % N
    const int i  = bi & (N - 1);
    const int jrow = (bi - i) + j0 + sub;    // b*N + j (x row of j)

    const f32x4 xi = *(const f32x4*)(x + (size_t)bi   * C + q * 4);
    const f32x4 xj = *(const f32x4*)(x + (size_t)jrow * C + q * 4);

    const float d0 = xi.x * xj.x;
    const float d1 = xi.y * xj.y;
    const float d2 = xi.z * xj.z;
    const float d3 = xi.w * xj.w;

    // max over the 64 channels of this row: lane-local then 16-lane DPP tree
    float m = fmaxf(fmaxf(d0, d1), fmaxf(d2, d3));
    m = fmaxf(m, dpp_mov<0xB1>(m));          // xor1
    m = fmaxf(m, dpp_mov<0x4E>(m));          // xor2
    m = fmaxf(m, dpp_mov<0x141>(m));         // row_half_mirror (8-group)
    m = fmaxf(m, dpp_mov<0x140>(m));         // row_mirror (16-group)

    const float e0 = __expf(d0 - m);
    const float e1 = __expf(d1 - m);
    const float e2 = __expf(d2 - m);
    const float e3 = __expf(d3 - m);

    float s = e0 + e1 + e2 + e3;
    s += dpp_mov<0xB1>(s);
    s += dpp_mov<0x4E>(s);
    s += dpp_mov<0x141>(s);
    s += dpp_mov<0x140>(s);

    const float inv = 1.0f / s;
    f32x4 o;
    o.x = e0 * inv; o.y = e1 * inv; o.z = e2 * inv; o.w = e3 * inv;
    __builtin_nontemporal_store(o, (f32x4*)(out + (size_t)R0 * C + (size_t)lane * 4));
}

extern "C" void kernel_launch(void* const* d_in, const int* in_sizes, int n_in,
                              void* d_out, int out_size, void* d_ws, size_t ws_size,
                              hipStream_t stream) {
    const float* h     = (const float*)d_in[0];
    const float* W     = (const float*)d_in[1];
    const float* b     = (const float*)d_in[2];
    const float* gamma = (const float*)d_in[3];
    const float* beta  = (const float*)d_in[4];
    float* out = (float*)d_out;
    float* x   = (float*)d_ws;               // B*N*C floats = 512 KB scratch

    // Kernel 1: B*N = 2048 rows, 4 rows (waves) per block -> 512 blocks.
    mlp_ln_kernel<<<(B * N) / 4, 256, 0, stream>>>(h, W, b, gamma, beta, x);

    // Kernel 2: B*N*N = 1,048,576 rows, 16 rows per block -> 65,536 blocks.
    softmax_outer_kernel<<<(B * N * N) / 16, 256, 0, stream>>>(x, out);
}